// Round 6
// baseline (466.537 us; speedup 1.0000x reference)
//
#include <hip/hip_runtime.h>

// SimpleRNN fused kernel for MI355X (gfx950).
// B=256, T=512, I=64, H=256, O=1, fp32.
//
// Decomposition: 256 blocks (one per batch row) x 512 threads.
// Lane (j = tid>>1, half = tid&1) owns W_hh[j][half*128 .. +127] (128 floats).
// h broadcast via padded LDS (R1 zero-conflict layout), one barrier/step.
//
// History:
// R1: padded LDS half-split (conflicts 1.34e8 -> 0, 608 -> 461 us).
// R2: 4-way k-split/1024thr regressed (not wave-latency-bound).
// R3-R5: three knobs (launch_bounds(512,1), asm pin, waves_per_eu(2,2))
//     all failed to lift VGPR_Count above 104. Counter forensics:
//     WRITE_SIZE=8KB => never spilled; per-step remat from L2 is
//     arithmetically impossible at observed speed => the weight arrays
//     live in AGPRs (invisible to VGPR_Count) with one extra VALU
//     (accvgpr_read) per weight use. VALU models of R1 AND R2 both match
//     measured VALUBusy under this hypothesis (~350 instr/thread/step).
// R6: shrink the per-thread persistent set instead of fighting the RA:
//     eliminate wi[32] + xbuf staging + per-step x prefetch by
//     precomputing the x-projection xw[t,j] in-kernel every 32 steps:
//     a register-tiled [32x64]@[64x256] GEMM reading a swizzled LDS copy
//     of W_ih (64KB) and xtile (8KB), writing xw tile (32KB). Per step
//     the x-term is ONE conflict-free b32 LDS read. Per-step removes
//     ~32 AGPR-reads + 32 FMA + 8 b128 reads + prefetch branch.

#define RNN_B 256
#define RNN_T 512
#define RNN_I 64
#define RNN_H 256
#define TILE_T 32
#define N_TILES (RNN_T / TILE_T)

// padded h layout: h[0..127] at [0..127], h[128..255] at [132..259]
#define HSTRIDE 132

__global__
__attribute__((amdgpu_flat_work_group_size(512, 512), amdgpu_waves_per_eu(2, 2)))
void rnn_fused_kernel(const float* __restrict__ x,     // [B,T,I]
                      const float* __restrict__ W_ih,  // [H,I]
                      const float* __restrict__ W_hh,  // [H,H]
                      const float* __restrict__ b_ih,  // [H]
                      const float* __restrict__ b_hh,  // [H]
                      const float* __restrict__ fc_W,  // [O,H], O=1
                      const float* __restrict__ fc_b,  // [O]
                      float* __restrict__ out)         // [B,O]
{
    const int b    = blockIdx.x;
    const int tid  = threadIdx.x;   // 0..511
    const int j    = tid >> 1;      // output hidden index 0..255
    const int half = tid & 1;       // which half of the k-reduction

    __shared__ float  hbuf[2][260];           // double-buffered h (padded)
    __shared__ float4 wih[RNN_H * 16];        // swizzled W_ih copy, 64 KB
    __shared__ float4 xtile[TILE_T * 16];     // x[b, t0..t0+31, :], 8 KB
    __shared__ float  xw[TILE_T * RNN_H];     // x-projection tile, 32 KB
    __shared__ float  red[8];

    // padded write index for h[j]
    const int jofs = j + ((j >> 7) << 2);

    // ---- stage W_ih into LDS, swizzled so GEMM reads are bank-spread ----
    // row jr, chunk c stored at float4 slot jr*16 + (c ^ ((jr>>2)&15)).
    // GEMM read pattern (lane l reads rows 4l+r): group8 = (c&7)^(l&7)
    // -> 8 lanes per 4-bank group, bandwidth-optimal.
    {
        const float4* src = reinterpret_cast<const float4*>(W_ih);
        #pragma unroll
        for (int it = 0; it < 8; ++it) {
            const int g  = tid + it * 512;    // 4096 float4s total
            const int jr = g >> 4;
            const int c  = g & 15;
            wih[jr * 16 + (c ^ ((jr >> 2) & 15))] = src[g];
        }
    }

    // ---- register-resident W_hh half-row (128 floats) ----
    float4 wh[32];  // W_hh[j][half*128 + 4c + {0..3}]
    {
        const float4* src = reinterpret_cast<const float4*>(W_hh + j * RNN_H + half * 128);
        #pragma unroll
        for (int c = 0; c < 32; ++c) wh[c] = src[c];
    }
    const float bias2 = b_ih[j] + b_hh[j];
    const float fcw   = fc_W[j];

    // ---- prologue: h0 = 0 ----
    if (half == 0) hbuf[0][jofs] = 0.0f;

    // GEMM lane mapping: lane owns 4 j-rows x 4 t-rows of the xw tile
    const int gj = (tid & 63) << 2;   // j0: 0,4,...,252
    const int gt = (tid >> 6) << 2;   // t0-in-tile: wave w -> 4w..4w+3

    float hj = 0.0f;  // this lane's h_new[j] (identical in lane pairs)

#define RNN_STEP(CUR, NXT, TT)                                                   \
    {                                                                            \
        const float xwv = xw[(TT) * RNN_H + j];  /* conflict-free b32 */         \
        float a0 = 0.f, a1 = 0.f, a2 = 0.f, a3 = 0.f;                            \
        const float4* hs = reinterpret_cast<const float4*>(&hbuf[CUR][half * HSTRIDE]); \
        _Pragma("unroll")                                                        \
        for (int c = 0; c < 32; ++c) {                                           \
            const float4 h4 = hs[c];   /* broadcast; halves on disjoint banks */ \
            a0 = fmaf(h4.x, wh[c].x, a0);                                        \
            a1 = fmaf(h4.y, wh[c].y, a1);                                        \
            a2 = fmaf(h4.z, wh[c].z, a2);                                        \
            a3 = fmaf(h4.w, wh[c].w, a3);                                        \
        }                                                                        \
        float partial = (a0 + a1) + (a2 + a3);                                   \
        partial += __shfl_xor(partial, 1, 64);   /* add partner half's part */   \
        const float z  = partial + xwv + bias2;                                  \
        const float zc = fminf(fmaxf(z, -10.f), 10.f);                           \
        const float e  = exp2f(zc * 2.8853900817779268f);     /* e^(2z) */       \
        const float hn = (e - 1.f) * __builtin_amdgcn_rcpf(e + 1.f);             \
        hj = hn;                                                                 \
        if (half == 0) hbuf[NXT][jofs] = hn;                                     \
        __syncthreads();                                                         \
    }

    for (int tile = 0; tile < N_TILES; ++tile) {
        const int t0 = tile * TILE_T;

        // ---- stage x[b, t0..t0+31, :] (coalesced, 1 float4/thread) ----
        {
            const float4* xs = reinterpret_cast<const float4*>(x)
                               + ((size_t)b * RNN_T + t0) * (RNN_I / 4);
            xtile[tid] = xs[tid];
        }
        __syncthreads();   // xtile ready (also covers wih/h0 on tile 0)

        // ---- tile GEMM: xw[t][j] = x[t,:] . W_ih[j,:]  (4t x 4j per lane) ----
        {
            float acc00=0.f,acc01=0.f,acc02=0.f,acc03=0.f;
            float acc10=0.f,acc11=0.f,acc12=0.f,acc13=0.f;
            float acc20=0.f,acc21=0.f,acc22=0.f,acc23=0.f;
            float acc30=0.f,acc31=0.f,acc32=0.f,acc33=0.f;
            #pragma unroll
            for (int c = 0; c < 16; ++c) {
                float4 w0 = wih[(gj + 0) * 16 + (c ^ (((gj + 0) >> 2) & 15))];
                float4 w1 = wih[(gj + 1) * 16 + (c ^ (((gj + 1) >> 2) & 15))];
                float4 w2 = wih[(gj + 2) * 16 + (c ^ (((gj + 2) >> 2) & 15))];
                float4 w3 = wih[(gj + 3) * 16 + (c ^ (((gj + 3) >> 2) & 15))];
                float4 x0 = xtile[(gt + 0) * 16 + c];   // wave-broadcast
                float4 x1 = xtile[(gt + 1) * 16 + c];
                float4 x2 = xtile[(gt + 2) * 16 + c];
                float4 x3 = xtile[(gt + 3) * 16 + c];
#define GEMM_ACC(A, XV, WV) \
                A = fmaf(XV.x, WV.x, A); A = fmaf(XV.y, WV.y, A); \
                A = fmaf(XV.z, WV.z, A); A = fmaf(XV.w, WV.w, A);
                GEMM_ACC(acc00, x0, w0) GEMM_ACC(acc01, x0, w1)
                GEMM_ACC(acc02, x0, w2) GEMM_ACC(acc03, x0, w3)
                GEMM_ACC(acc10, x1, w0) GEMM_ACC(acc11, x1, w1)
                GEMM_ACC(acc12, x1, w2) GEMM_ACC(acc13, x1, w3)
                GEMM_ACC(acc20, x2, w0) GEMM_ACC(acc21, x2, w1)
                GEMM_ACC(acc22, x2, w2) GEMM_ACC(acc23, x2, w3)
                GEMM_ACC(acc30, x3, w0) GEMM_ACC(acc31, x3, w1)
                GEMM_ACC(acc32, x3, w2) GEMM_ACC(acc33, x3, w3)
#undef GEMM_ACC
            }
            float4* xw4 = reinterpret_cast<float4*>(xw);
            const int jc = gj >> 2;   // = tid & 63
            xw4[(gt + 0) * 64 + jc] = make_float4(acc00, acc01, acc02, acc03);
            xw4[(gt + 1) * 64 + jc] = make_float4(acc10, acc11, acc12, acc13);
            xw4[(gt + 2) * 64 + jc] = make_float4(acc20, acc21, acc22, acc23);
            xw4[(gt + 3) * 64 + jc] = make_float4(acc30, acc31, acc32, acc33);
        }
        __syncthreads();   // xw ready

        // ---- 32 recurrence steps (parity-fixed 2x unroll) ----
        for (int tt = 0; tt < TILE_T; tt += 2) {
            RNN_STEP(0, 1, tt)
            RNN_STEP(1, 0, tt + 1)
        }
    }
#undef RNN_STEP

    // ---- epilogue: out[b] = sum_j h_T[j]*fc_W[j] + fc_b ----
    float term = (half == 0) ? hj * fcw : 0.0f;
    #pragma unroll
    for (int s = 1; s < 64; s <<= 1) term += __shfl_xor(term, s, 64);
    const int wid = tid >> 6;
    if ((tid & 63) == 0) red[wid] = term;
    __syncthreads();
    if (tid == 0) {
        float s = 0.f;
        #pragma unroll
        for (int w = 0; w < 8; ++w) s += red[w];
        out[b] = s + fc_b[0];
    }
}

extern "C" void kernel_launch(void* const* d_in, const int* in_sizes, int n_in,
                              void* d_out, int out_size, void* d_ws, size_t ws_size,
                              hipStream_t stream) {
    const float* x    = (const float*)d_in[0];
    const float* W_ih = (const float*)d_in[1];
    const float* W_hh = (const float*)d_in[2];
    const float* b_ih = (const float*)d_in[3];
    const float* b_hh = (const float*)d_in[4];
    const float* fc_W = (const float*)d_in[5];
    const float* fc_b = (const float*)d_in[6];
    float* out = (float*)d_out;

    rnn_fused_kernel<<<RNN_B, 512, 0, stream>>>(x, W_ih, W_hh, b_ih, b_hh, fc_W, fc_b, out);
}

// Round 7
// 319.474 us; speedup vs baseline: 1.4603x; 1.4603x over previous
//
#include <hip/hip_runtime.h>

// SimpleRNN fused kernel for MI355X (gfx950).
// B=256, T=512, I=64, H=256, O=1, fp32.
//
// History:
// R1: padded LDS half-split (conflicts 1.34e8 -> 0, 608 -> 461 us).
// R2: 4-way k-split/1024thr regressed (not wave-latency-bound).
// R3-R5: register knobs all failed to lift VGPR_Count (AGPR stash);
//     time pinned at ~2400 cyc/step regardless.
// R6: in-kernel xw GEMM tile spilled (WRITE_SIZE 8KB->33.8MB), regressed.
// R7: root cause identified: LDS ISSUE BOUND. Old structure: every wave
//     broadcast-reads ALL of h as 32 ds_read_b128 + 8 for x = 320 LDS
//     instrs/CU/step ~= 2200-3800 cyc on the one LDS pipe = measured step
//     time. Hard floor unless one read feeds multiple j's. New mapping:
//     lane (g=l>>3, s=l&7) of wave w owns j-quad 32w+4g..+3 and k-seg
//     32s..+31: each h-float4 feeds 4 accumulators -> 8 h-reads + 2
//     x-reads + 1 write per wave per step = ~88 LDS instrs/CU/step (3.6x
//     cut). Partials combined across the 8 k-seg lanes via 3-step shfl
//     reduce-scatter; each lane finalizes one j (s<4 writes).
//     h LDS layout slot(j) = j + 4*(j>>5): per-instr banks 4(s+c) mod 32
//     -> 8 disjoint 4-bank groups, conflict-free. x staged per 32-step
//     tile from a register-prefetched coalesced load.

#define RNN_B 256
#define RNN_T 512
#define RNN_I 64
#define RNN_H 256
#define TILE_T 32
#define N_TILES (RNN_T / TILE_T)

__global__
__attribute__((amdgpu_flat_work_group_size(512, 512), amdgpu_waves_per_eu(2, 2)))
void rnn_fused_kernel(const float* __restrict__ x,     // [B,T,I]
                      const float* __restrict__ W_ih,  // [H,I]
                      const float* __restrict__ W_hh,  // [H,H]
                      const float* __restrict__ b_ih,  // [H]
                      const float* __restrict__ b_hh,  // [H]
                      const float* __restrict__ fc_W,  // [O,H], O=1
                      const float* __restrict__ fc_b,  // [O]
                      float* __restrict__ out)         // [B,O]
{
    const int b   = blockIdx.x;
    const int tid = threadIdx.x;    // 0..511
    const int w   = tid >> 6;       // wave 0..7
    const int l   = tid & 63;       // lane
    const int g   = l >> 3;         // j-quad within wave, 0..7
    const int s   = l & 7;          // k-segment, 0..7
    const int j0  = w * 32 + g * 4; // first j of this lane's quad

    __shared__ float hbuf[2][288];        // padded h: slot(j) = j + 4*(j>>5)
    __shared__ float xt[TILE_T][RNN_I];   // x tile: 32 timesteps, 8 KB
    __shared__ float red[8];

    // ---- persistent weights: 4 j-rows x 32-k segment ----
    float4 wh[4][8];   // wh[jj][c] = W_hh[j0+jj][32s + 4c .. +3]
    float4 wi[4][2];   // wi[jj][c] = W_ih[j0+jj][8s + 4c .. +3]
    #pragma unroll
    for (int jj = 0; jj < 4; ++jj) {
        const float4* src = reinterpret_cast<const float4*>(W_hh + (j0 + jj) * RNN_H + 32 * s);
        #pragma unroll
        for (int c = 0; c < 8; ++c) wh[jj][c] = src[c];
    }
    #pragma unroll
    for (int jj = 0; jj < 4; ++jj) {
        const float4* src = reinterpret_cast<const float4*>(W_ih + (j0 + jj) * RNN_I + 8 * s);
        #pragma unroll
        for (int c = 0; c < 2; ++c) wi[jj][c] = src[c];
    }

    // lane finalizes j_fin = j0 + jjsel after the reduce-scatter
    const int   jjsel = ((s & 1) << 1) | ((s >> 1) & 1);
    const int   j_fin = j0 + jjsel;
    const int   jslot = j_fin + 4 * w;          // slot(j_fin): j_fin>>5 == w
    const float bias2 = b_ih[j_fin] + b_hh[j_fin];
    const float fcw   = fc_W[j_fin];

    // ---- prologue: h0 = 0; prefetch x tile 0 into registers ----
    if (tid < 288) hbuf[0][tid] = 0.0f;
    const float4* xs = reinterpret_cast<const float4*>(x + (size_t)b * RNN_T * RNN_I);
    float4 xreg = xs[tid];   // tile 0 (512 float4 = 32 x 64 floats)

    float hj = 0.0f;  // this lane's h_new[j_fin]

#define RNN_STEP(CUR, NXT, TT)                                                  \
    {                                                                           \
        const float4* hs = reinterpret_cast<const float4*>(hbuf[CUR]) + 9 * s;  \
        const float4* xp = reinterpret_cast<const float4*>(&xt[TT][0]) + 2 * s; \
        float p0 = 0.f, p1 = 0.f, p2 = 0.f, p3 = 0.f;                           \
        _Pragma("unroll")                                                       \
        for (int c = 0; c < 8; ++c) {                                           \
            const float4 h4 = hs[c];  /* 8 addrs, 8 disjoint bank groups */     \
            p0 = fmaf(h4.x, wh[0][c].x, p0); p0 = fmaf(h4.y, wh[0][c].y, p0);   \
            p0 = fmaf(h4.z, wh[0][c].z, p0); p0 = fmaf(h4.w, wh[0][c].w, p0);   \
            p1 = fmaf(h4.x, wh[1][c].x, p1); p1 = fmaf(h4.y, wh[1][c].y, p1);   \
            p1 = fmaf(h4.z, wh[1][c].z, p1); p1 = fmaf(h4.w, wh[1][c].w, p1);   \
            p2 = fmaf(h4.x, wh[2][c].x, p2); p2 = fmaf(h4.y, wh[2][c].y, p2);   \
            p2 = fmaf(h4.z, wh[2][c].z, p2); p2 = fmaf(h4.w, wh[2][c].w, p2);   \
            p3 = fmaf(h4.x, wh[3][c].x, p3); p3 = fmaf(h4.y, wh[3][c].y, p3);   \
            p3 = fmaf(h4.z, wh[3][c].z, p3); p3 = fmaf(h4.w, wh[3][c].w, p3);   \
        }                                                                       \
        _Pragma("unroll")                                                       \
        for (int c = 0; c < 2; ++c) {                                           \
            const float4 x4 = xp[c];                                            \
            p0 = fmaf(x4.x, wi[0][c].x, p0); p0 = fmaf(x4.y, wi[0][c].y, p0);   \
            p0 = fmaf(x4.z, wi[0][c].z, p0); p0 = fmaf(x4.w, wi[0][c].w, p0);   \
            p1 = fmaf(x4.x, wi[1][c].x, p1); p1 = fmaf(x4.y, wi[1][c].y, p1);   \
            p1 = fmaf(x4.z, wi[1][c].z, p1); p1 = fmaf(x4.w, wi[1][c].w, p1);   \
            p2 = fmaf(x4.x, wi[2][c].x, p2); p2 = fmaf(x4.y, wi[2][c].y, p2);   \
            p2 = fmaf(x4.z, wi[2][c].z, p2); p2 = fmaf(x4.w, wi[2][c].w, p2);   \
            p3 = fmaf(x4.x, wi[3][c].x, p3); p3 = fmaf(x4.y, wi[3][c].y, p3);   \
            p3 = fmaf(x4.z, wi[3][c].z, p3); p3 = fmaf(x4.w, wi[3][c].w, p3);   \
        }                                                                       \
        /* reduce-scatter across the 8 k-seg lanes (xor 1,2,4) */               \
        const bool sb0 = (s & 1) != 0;                                          \
        const float g0 = sb0 ? p0 : p2, g1 = sb0 ? p1 : p3;   /* give away */   \
        const float k0 = sb0 ? p2 : p0, k1 = sb0 ? p3 : p1;   /* keep     */    \
        const float r0 = k0 + __shfl_xor(g0, 1, 64);                            \
        const float r1 = k1 + __shfl_xor(g1, 1, 64);                            \
        const bool sb1 = (s & 2) != 0;                                          \
        const float g2 = sb1 ? r0 : r1;                                         \
        const float k2 = sb1 ? r1 : r0;                                         \
        const float u  = k2 + __shfl_xor(g2, 2, 64);                            \
        const float v  = u + __shfl_xor(u, 4, 64);   /* full 256-k sum */       \
        const float z  = v + bias2;                                             \
        const float zc = fminf(fmaxf(z, -10.f), 10.f);                          \
        const float e  = exp2f(zc * 2.8853900817779268f);     /* e^(2z) */      \
        const float hn = (e - 1.f) * __builtin_amdgcn_rcpf(e + 1.f);            \
        hj = hn;                                                                \
        if (s < 4) hbuf[NXT][jslot] = hn;   /* 32 lanes, 32 consec banks */     \
        __syncthreads();                                                        \
    }

    for (int tile = 0; tile < N_TILES; ++tile) {
        // stage current x tile from the prefetch register (prev barrier
        // guarantees all reads of the old tile are done)
        reinterpret_cast<float4*>(xt)[tid] = xreg;
        if (tile + 1 < N_TILES) xreg = xs[(tile + 1) * 512 + tid];  // hide ~32 steps
        __syncthreads();   // xt (and h0/weights on tile 0) ready

        for (int tt = 0; tt < TILE_T; tt += 2) {
            RNN_STEP(0, 1, tt)
            RNN_STEP(1, 0, tt + 1)
        }
    }
#undef RNN_STEP

    // ---- epilogue: out[b] = sum_j h_T[j]*fc_W[j] + fc_b ----
    float term = (s < 4) ? hj * fcw : 0.0f;   // each j counted once
    #pragma unroll
    for (int d = 1; d < 64; d <<= 1) term += __shfl_xor(term, d, 64);
    if (l == 0) red[w] = term;
    __syncthreads();
    if (tid == 0) {
        float sum = 0.f;
        #pragma unroll
        for (int ww = 0; ww < 8; ++ww) sum += red[ww];
        out[b] = sum + fc_b[0];
    }
}

extern "C" void kernel_launch(void* const* d_in, const int* in_sizes, int n_in,
                              void* d_out, int out_size, void* d_ws, size_t ws_size,
                              hipStream_t stream) {
    const float* x    = (const float*)d_in[0];
    const float* W_ih = (const float*)d_in[1];
    const float* W_hh = (const float*)d_in[2];
    const float* b_ih = (const float*)d_in[3];
    const float* b_hh = (const float*)d_in[4];
    const float* fc_W = (const float*)d_in[5];
    const float* fc_b = (const float*)d_in[6];
    float* out = (float*)d_out;

    rnn_fused_kernel<<<RNN_B, 512, 0, stream>>>(x, W_ih, W_hh, b_ih, b_hh, fc_W, fc_b, out);
}